// Round 13
// baseline (322.993 us; speedup 1.0000x reference)
//
#include <hip/hip_runtime.h>
#include <hip/hip_bf16.h>

// Problem constants: B=16, N=1024, D=768 -> T=16384 tokens.
#define T_TOK   16384
#define D_DIM   768
#define ROWB    1536          // bytes per row (768 * 2B bf16)
#define INV_TEMP (1.0f/0.07f)
#define XROWS   17152
#define XALL_BYTES (XROWS * ROWB)

typedef __bf16 bf16x8 __attribute__((ext_vector_type(8)));
typedef float  f32x4  __attribute__((ext_vector_type(4)));
typedef unsigned int u32;
typedef unsigned short u16;

__device__ __forceinline__ u32 f2u(float f) {
    u32 b = __float_as_uint(f);
    return (b & 0x80000000u) ? ~b : (b | 0x80000000u);
}
__device__ __forceinline__ float u2f(u32 u) {
    u32 b = (u & 0x80000000u) ? (u & 0x7FFFFFFFu) : ~u;
    return __uint_as_float(b);
}
__device__ __forceinline__ u16 f2bf(float f) {
    __hip_bfloat16 h = __float2bfloat16(f);
    u16 u; __builtin_memcpy(&u, &h, 2); return u;
}

__device__ __forceinline__ void gload16(const void* g, void* l) {
    __builtin_amdgcn_global_load_lds((const __attribute__((address_space(1))) u32*)g,
                                     (__attribute__((address_space(3))) u32*)l,
                                     16, 0, 0);
}

// ============================================================================
// K1: class-wise prefix scan + fused zeroing of rowmax/colmax.
// meta[0]=R, meta[1]=F, meta[2]=Rpad(256-aligned).
// ============================================================================
__global__ void k_scan(const int* __restrict__ labels, int* __restrict__ pos,
                       int* __restrict__ meta, u32* __restrict__ rowmax)
{
    __shared__ int sr[256], sf[256];
    const int t = threadIdx.x;
    for (int i = t; i < 32768; i += 256) rowmax[i] = 0u;
    const int base = t * 64;
    int cr = 0, cf = 0;
    for (int i = 0; i < 64; ++i) {
        int v = labels[base + i];
        cr += (v == 0);
        cf += (v == 1);
    }
    sr[t] = cr; sf[t] = cf;
    __syncthreads();
    if (t == 0) {
        int ar = 0, af = 0;
        for (int i = 0; i < 256; ++i) {
            int r = sr[i]; sr[i] = ar; ar += r;
            int f = sf[i]; sf[i] = af; af += f;
        }
        meta[0] = ar;
        meta[1] = af;
        meta[2] = (ar + 255) & ~255;
    }
    __syncthreads();
    int pr = sr[t], pf = sf[t];
    for (int i = 0; i < 64; ++i) {
        int v = labels[base + i];
        pos[base + i] = (v == 0) ? pr++ : pf++;
    }
}

// ============================================================================
// K2: L2-normalize rows (float4 loads), bf16 convert (ushort4 stores),
// scatter compacted by class.
// ============================================================================
__global__ void k_norm(const float* __restrict__ x, const int* __restrict__ labels,
                       const int* __restrict__ pos, const int* __restrict__ meta,
                       __hip_bfloat16* __restrict__ Xall)
{
    const int row = blockIdx.x;
    const int t = threadIdx.x;
    const float4* xr = (const float4*)(x + (size_t)row * D_DIM);
    float4 v = make_float4(0.f, 0.f, 0.f, 0.f);
    float ss = 0.f;
    if (t < 192) {
        v = xr[t];
        ss = v.x * v.x + v.y * v.y + v.z * v.z + v.w * v.w;
    }
    #pragma unroll
    for (int m = 32; m >= 1; m >>= 1) ss += __shfl_xor(ss, m);
    __shared__ float sred[4];
    if ((t & 63) == 0) sred[t >> 6] = ss;
    __syncthreads();
    float tot = sred[0] + sred[1] + sred[2] + sred[3];
    float inv = 1.0f / fmaxf(sqrtf(tot), 1e-12f);
    if (t < 192) {
        int lab = labels[row];
        int base = (lab == 0) ? pos[row] : (meta[2] + pos[row]);
        ushort4 o;
        o.x = f2bf(v.x * inv); o.y = f2bf(v.y * inv);
        o.z = f2bf(v.z * inv); o.w = f2bf(v.w * inv);
        ((ushort4*)(Xall + (size_t)base * D_DIM))[t] = o;
    }
}

// ============================================================================
// K3 (round 13): m97-faithful SINGLE-BUFFER structure, occupancy-maximized.
// 128x128 tile, 4 waves 2x2, BK=64, ONE 32 KiB LDS buffer (A 16K + B 16K)
// -> 4 blocks/CU (LDS 32K, VGPR ~88), 16 waves/CU = 4/SIMD. Cross-block TLP
// fills the CU pipes during each block's stage/barrier stalls (the only lever
// that has measurably helped this kernel: r6->r7 1->2 blocks/CU = +16%).
// Per K-step (counting-free, rigorous):
//   STAGE(t)   8x gload_lds (A 4 + B 4), pre-swizzled source, linear dest
//   DRAIN0     "s_waitcnt vmcnt(0); s_barrier"  (RAW: own stages forced,
//              barrier publishes; also forces epilogue atomics -- harmless)
//   16x ds_read_b128 + 32x MFMA (setprio-wrapped)
//   BAR        plain s_barrier (WAR: reads consumed -- lgkm drained before
//              each wave's MFMAs which precede its arrival; next STAGE's
//              writes issue only after)
// Swizzle: LDS[row][c] holds source chunk c^(row&7) (8 chunks of 16B/row);
// read chunk = (lg^(li&7)) -- the r2-r12-verified pair. Streaming bn via
// (bm,grp) decode, per-bn register epilogue, XCD-clustered: per XCD A panels
// 8 x 192 KiB = 1.5 MB + ~16 live B panels ~3 MB -> L2-resident.
// ============================================================================
#define MFMA16(a,b,c) __builtin_amdgcn_mfma_f32_16x16x32_bf16(a,b,c,0,0,0)

// step s -> (bi=s/12, kt=s%12); wave-uniform scalar math.
#define STAGE(s) do { \
    int bi_ = (s)/12, kt_ = (s)%12; \
    const char* ap_ = Ab + soff + kt_*128; \
    gload16(ap_,            ldsA + wq); \
    gload16(ap_ + 32*ROWB,  ldsA + wq + 4096); \
    gload16(ap_ + 64*ROWB,  ldsA + wq + 8192); \
    gload16(ap_ + 96*ROWB,  ldsA + wq + 12288); \
    const char* bp_ = Bb + (size_t)(grp + Gm*bi_) * (128*ROWB) + soff + kt_*128; \
    gload16(bp_,            ldsB + wq); \
    gload16(bp_ + 32*ROWB,  ldsB + wq + 4096); \
    gload16(bp_ + 64*ROWB,  ldsB + wq + 8192); \
    gload16(bp_ + 96*ROWB,  ldsB + wq + 12288); } while(0)

#define DRAIN0 asm volatile("s_waitcnt vmcnt(0)\n\ts_barrier" ::: "memory")
#define BAR    __builtin_amdgcn_s_barrier()

#define LOADAB do { \
    _Pragma("unroll") \
    for (int mm = 0; mm < 4; ++mm) { \
        afr[mm][0] = *(const bf16x8*)(ldsA + aBase + mm*2048 + cb0); \
        afr[mm][1] = *(const bf16x8*)(ldsA + aBase + mm*2048 + cb1); } \
    _Pragma("unroll") \
    for (int nn = 0; nn < 4; ++nn) { \
        bfr[nn][0] = *(const bf16x8*)(ldsB + bBase + nn*2048 + cb0); \
        bfr[nn][1] = *(const bf16x8*)(ldsB + bBase + nn*2048 + cb1); } } while(0)

__global__ __launch_bounds__(256, 4) void k_gemm(const __hip_bfloat16* __restrict__ Xall,
                                                 const int* __restrict__ meta,
                                                 u32* __restrict__ rowmax,
                                                 u32* __restrict__ colmax)
{
    const int R = meta[0], Fc = meta[1], Rpad = meta[2];
    const int nbm = (R + 127) >> 7;
    const int nbn = (Fc + 127) >> 7;
    if (nbm == 0 || nbn == 0) return;
    const int Gm = (nbn < 16) ? nbn : 16;
    const int P  = nbm * Gm;

    __shared__ __align__(16) char lds[32768];
    char* ldsA = lds;
    char* ldsB = lds + 16384;

    const int tid = threadIdx.x;
    const int w  = tid >> 6, l = tid & 63;
    const int wm = w >> 1, wn = w & 1;
    const int lg = l >> 4, li = l & 15;
    const int wq = w * 1024;

    // staging geometry: thread covers rows srow+{0,32,64,96}, 8 chunks of
    // 16B per row; pre-swizzled source chunk (tid&7)^(srow&7), linear dest.
    const int srow = tid >> 3;               // 0..31
    const int ch   = ((tid & 7) ^ (srow & 7)) * 16;
    const int soff = srow * ROWB + ch;

    const char* Bb = (const char*)Xall + (size_t)Rpad * ROWB;

    // MFMA read geometry (r7-verified)
    const int aBase = (wm * 64 + li) * 128;
    const int bBase = (wn * 64 + li) * 128;
    const int sw  = li & 7;
    const int cb0 = (lg ^ sw) * 16;
    const int cb1 = ((4 + lg) ^ sw) * 16;

    const float MASKED = -3.0f;
    f32x4 acc[4][4];
    #pragma unroll
    for (int m = 0; m < 4; ++m)
        #pragma unroll
        for (int n = 0; n < 4; ++n)
            acc[m][n] = (f32x4){0.f, 0.f, 0.f, 0.f};

    bf16x8 afr[4][2], bfr[4][2];

    #pragma unroll 1
    for (int p = blockIdx.x; p < P; p += (int)gridDim.x) {
        // ---- decode (bm, grp); XCD-clustered in the common case ----
        int bm, grp;
        if (nbm == 64 && Gm == 16) {
            int xcd = p & 7, i = p >> 3;
            bm = ((i & 7) << 3) + xcd;   // XCD x owns bm == x (mod 8)
            grp = i >> 3;                // [0,16)
        } else {
            bm = p % nbm; grp = p / nbm;
        }
        const int nt = (nbn - grp + Gm - 1) / Gm;
        const int NS = 12 * nt;

        const char* Ab = (const char*)Xall + (size_t)(bm * 128) * ROWB;

        #pragma unroll 1
        for (int th = 0; th < NS; ++th) {
            STAGE(th);
            DRAIN0;                       // stage complete, published
            LOADAB;
            __builtin_amdgcn_s_setprio(1);
            #pragma unroll
            for (int mm = 0; mm < 4; ++mm)
                #pragma unroll
                for (int nn = 0; nn < 4; ++nn) {
                    acc[mm][nn] = MFMA16(afr[mm][0], bfr[nn][0], acc[mm][nn]);
                    acc[mm][nn] = MFMA16(afr[mm][1], bfr[nn][1], acc[mm][nn]);
                }
            __builtin_amdgcn_s_setprio(0);

            if ((th % 12) == 11) {
                // ---- per-bn register epilogue (reads acc only) ----
                const int bnv = grp + Gm * (th / 12);
                #pragma unroll
                for (int m = 0; m < 4; ++m)
                    #pragma unroll
                    for (int reg = 0; reg < 4; ++reg) {
                        float v = MASKED;
                        #pragma unroll
                        for (int n = 0; n < 4; ++n) {
                            int gc = bnv * 128 + wn * 64 + n * 16 + li;
                            v = fmaxf(v, (gc < Fc) ? acc[m][n][reg] : MASKED);
                        }
                        v = fmaxf(v, __shfl_xor(v, 1));
                        v = fmaxf(v, __shfl_xor(v, 2));
                        v = fmaxf(v, __shfl_xor(v, 4));
                        v = fmaxf(v, __shfl_xor(v, 8));
                        int gr = bm * 128 + wm * 64 + m * 16 + lg * 4 + reg;
                        if (li == 0 && gr < R) atomicMax(&rowmax[gr], f2u(v));
                    }
                #pragma unroll
                for (int n = 0; n < 4; ++n) {
                    float v = MASKED;
                    #pragma unroll
                    for (int m = 0; m < 4; ++m)
                        #pragma unroll
                        for (int reg = 0; reg < 4; ++reg) {
                            int gr = bm * 128 + wm * 64 + m * 16 + lg * 4 + reg;
                            v = fmaxf(v, (gr < R) ? acc[m][n][reg] : MASKED);
                        }
                    v = fmaxf(v, __shfl_xor(v, 16));
                    v = fmaxf(v, __shfl_xor(v, 32));
                    int gc = bnv * 128 + wn * 64 + n * 16 + li;
                    if (lg == 0 && gc < Fc) atomicMax(&colmax[gc], f2u(v));
                }
                #pragma unroll
                for (int m = 0; m < 4; ++m)
                    #pragma unroll
                    for (int n = 0; n < 4; ++n)
                        acc[m][n] = (f32x4){0.f, 0.f, 0.f, 0.f};
            }
            BAR;                          // all reads of buffer done
        }
    }
}

// ============================================================================
// K4: maxes -> loss, masked means, scalar out.
// ============================================================================
__global__ void k_final(const u32* __restrict__ rowmax, const u32* __restrict__ colmax,
                        const int* __restrict__ meta, float* __restrict__ out)
{
    const int R = meta[0], Fc = meta[1];
    const int t = threadIdx.x;
    float sr = 0.f, sf = 0.f;
    for (int i = t; i < R; i += 256) {
        u32 u = rowmax[i];
        float m = (u == 0u) ? -1e9f : u2f(u) * INV_TEMP;
        float sg = 1.0f / (1.0f + expf(-m));
        sr += -logf(1.0f - sg + 1e-6f);
    }
    for (int i = t; i < Fc; i += 256) {
        u32 u = colmax[i];
        float m = (u == 0u) ? -1e9f : u2f(u) * INV_TEMP;
        float sg = 1.0f / (1.0f + expf(-m));
        sf += -logf(1.0f - sg + 1e-6f);
    }
    #pragma unroll
    for (int msk = 32; msk >= 1; msk >>= 1) {
        sr += __shfl_xor(sr, msk);
        sf += __shfl_xor(sf, msk);
    }
    __shared__ float r4[4], f4[4];
    if ((t & 63) == 0) { r4[t >> 6] = sr; f4[t >> 6] = sf; }
    __syncthreads();
    if (t == 0) {
        float a = (r4[0] + r4[1] + r4[2] + r4[3]) / (float)((R > 0) ? R : 1);
        float b = (f4[0] + f4[1] + f4[2] + f4[3]) / (float)((Fc > 0) ? Fc : 1);
        out[0] = 0.5f * (a + b);
    }
}

// ============================================================================
extern "C" void kernel_launch(void* const* d_in, const int* in_sizes, int n_in,
                              void* d_out, int out_size, void* d_ws, size_t ws_size,
                              hipStream_t stream)
{
    (void)in_sizes; (void)n_in; (void)out_size; (void)ws_size;
    const float* x    = (const float*)d_in[0];
    const int* labels = (const int*)d_in[1];
    float* out        = (float*)d_out;

    char* ws = (char*)d_ws;
    int* meta = (int*)ws;
    int* pos  = (int*)(ws + 256);
    __hip_bfloat16* Xall = (__hip_bfloat16*)(ws + 131072);
    u32* rowmax = (u32*)(ws + 131072 + XALL_BYTES);
    u32* colmax = rowmax + 16384;

    k_scan<<<1, 256, 0, stream>>>(labels, pos, meta, rowmax);
    k_norm<<<T_TOK, 256, 0, stream>>>(x, labels, pos, meta, Xall);
    k_gemm<<<1024, 256, 0, stream>>>(Xall, meta, rowmax, colmax);
    k_final<<<1, 256, 0, stream>>>(rowmax, colmax, meta, out);
}

// Round 14
// 196.597 us; speedup vs baseline: 1.6429x; 1.6429x over previous
//
#include <hip/hip_runtime.h>
#include <hip/hip_bf16.h>

// Problem constants: B=16, N=1024, D=768 -> T=16384 tokens.
#define T_TOK   16384
#define D_DIM   768
#define ROWB    1536          // bytes per row (768 * 2B bf16)
#define INV_TEMP (1.0f/0.07f)
#define XROWS   17152
#define XALL_BYTES (XROWS * ROWB)

typedef __bf16 bf16x8 __attribute__((ext_vector_type(8)));
typedef float  f32x4  __attribute__((ext_vector_type(4)));
typedef unsigned int u32;
typedef unsigned short u16;

__device__ __forceinline__ u32 f2u(float f) {
    u32 b = __float_as_uint(f);
    return (b & 0x80000000u) ? ~b : (b | 0x80000000u);
}
__device__ __forceinline__ float u2f(u32 u) {
    u32 b = (u & 0x80000000u) ? (u & 0x7FFFFFFFu) : ~u;
    return __uint_as_float(b);
}
__device__ __forceinline__ u16 f2bf(float f) {
    __hip_bfloat16 h = __float2bfloat16(f);
    u16 u; __builtin_memcpy(&u, &h, 2); return u;
}

__device__ __forceinline__ void gload16(const void* g, void* l) {
    __builtin_amdgcn_global_load_lds((const __attribute__((address_space(1))) u32*)g,
                                     (__attribute__((address_space(3))) u32*)l,
                                     16, 0, 0);
}

// ============================================================================
// K1: class-wise prefix scan + fused zeroing of rowmax/colmax.
// meta[0]=R, meta[1]=F, meta[2]=Rpad(256-aligned).
// ============================================================================
__global__ void k_scan(const int* __restrict__ labels, int* __restrict__ pos,
                       int* __restrict__ meta, u32* __restrict__ rowmax)
{
    __shared__ int sr[256], sf[256];
    const int t = threadIdx.x;
    for (int i = t; i < 32768; i += 256) rowmax[i] = 0u;
    const int base = t * 64;
    int cr = 0, cf = 0;
    for (int i = 0; i < 64; ++i) {
        int v = labels[base + i];
        cr += (v == 0);
        cf += (v == 1);
    }
    sr[t] = cr; sf[t] = cf;
    __syncthreads();
    if (t == 0) {
        int ar = 0, af = 0;
        for (int i = 0; i < 256; ++i) {
            int r = sr[i]; sr[i] = ar; ar += r;
            int f = sf[i]; sf[i] = af; af += f;
        }
        meta[0] = ar;
        meta[1] = af;
        meta[2] = (ar + 255) & ~255;
    }
    __syncthreads();
    int pr = sr[t], pf = sf[t];
    for (int i = 0; i < 64; ++i) {
        int v = labels[base + i];
        pos[base + i] = (v == 0) ? pr++ : pf++;
    }
}

// ============================================================================
// K2: L2-normalize, wave-per-row (4 rows/block): 64 lanes x 3 float4 = 768
// floats; pure shuffle reduce (no LDS, no block barrier, no idle lanes).
// ============================================================================
__global__ void k_norm(const float* __restrict__ x, const int* __restrict__ labels,
                       const int* __restrict__ pos, const int* __restrict__ meta,
                       __hip_bfloat16* __restrict__ Xall)
{
    const int t = threadIdx.x;
    const int wv = t >> 6, ln = t & 63;
    const int row = blockIdx.x * 4 + wv;
    const float4* xr = (const float4*)(x + (size_t)row * D_DIM);
    float4 v0 = xr[ln], v1 = xr[ln + 64], v2 = xr[ln + 128];
    float ss = v0.x*v0.x + v0.y*v0.y + v0.z*v0.z + v0.w*v0.w
             + v1.x*v1.x + v1.y*v1.y + v1.z*v1.z + v1.w*v1.w
             + v2.x*v2.x + v2.y*v2.y + v2.z*v2.z + v2.w*v2.w;
    #pragma unroll
    for (int m = 32; m >= 1; m >>= 1) ss += __shfl_xor(ss, m);
    float inv = 1.0f / fmaxf(sqrtf(ss), 1e-12f);
    int lab = labels[row];
    int base = (lab == 0) ? pos[row] : (meta[2] + pos[row]);
    ushort4* dst = (ushort4*)(Xall + (size_t)base * D_DIM);
    ushort4 o0, o1, o2;
    o0.x = f2bf(v0.x*inv); o0.y = f2bf(v0.y*inv); o0.z = f2bf(v0.z*inv); o0.w = f2bf(v0.w*inv);
    o1.x = f2bf(v1.x*inv); o1.y = f2bf(v1.y*inv); o1.z = f2bf(v1.z*inv); o1.w = f2bf(v1.w*inv);
    o2.x = f2bf(v2.x*inv); o2.y = f2bf(v2.y*inv); o2.z = f2bf(v2.z*inv); o2.w = f2bf(v2.w*inv);
    dst[ln]       = o0;
    dst[ln + 64]  = o1;
    dst[ln + 128] = o2;
}

// ============================================================================
// K3 (round 14): r13 structure (m97-faithful single 32 KiB buffer, 128x128,
// 4 waves 2x2, BK=64, counting-free DRAIN0+BAR per K-step) with the spill
// fixed: __launch_bounds__(256,2) (cap 256 VGPR -- the r7/r10/r12 setting
// that produced clean 88-VGPR binaries). Expected alloc ~110-130 VGPR ->
// 4 waves/SIMD; LDS 32 KiB allows 5 blocks/CU -> occupancy 3-4 blocks/CU
// (m97's regime). r13's 290us was pure scratch-spill (VGPR forced to 64,
// WRITE_SIZE 503 MB); structure itself verified correct (absmax 0).
// ============================================================================
#define MFMA16(a,b,c) __builtin_amdgcn_mfma_f32_16x16x32_bf16(a,b,c,0,0,0)

// step s -> (bi=s/12, kt=s%12); wave-uniform scalar math.
#define STAGE(s) do { \
    int bi_ = (s)/12, kt_ = (s)%12; \
    const char* ap_ = Ab + soff + kt_*128; \
    gload16(ap_,            ldsA + wq); \
    gload16(ap_ + 32*ROWB,  ldsA + wq + 4096); \
    gload16(ap_ + 64*ROWB,  ldsA + wq + 8192); \
    gload16(ap_ + 96*ROWB,  ldsA + wq + 12288); \
    const char* bp_ = Bb + (size_t)(grp + Gm*bi_) * (128*ROWB) + soff + kt_*128; \
    gload16(bp_,            ldsB + wq); \
    gload16(bp_ + 32*ROWB,  ldsB + wq + 4096); \
    gload16(bp_ + 64*ROWB,  ldsB + wq + 8192); \
    gload16(bp_ + 96*ROWB,  ldsB + wq + 12288); } while(0)

#define DRAIN0 asm volatile("s_waitcnt vmcnt(0)\n\ts_barrier" ::: "memory")
#define BAR    __builtin_amdgcn_s_barrier()

#define LOADAB do { \
    _Pragma("unroll") \
    for (int mm = 0; mm < 4; ++mm) { \
        afr[mm][0] = *(const bf16x8*)(ldsA + aBase + mm*2048 + cb0); \
        afr[mm][1] = *(const bf16x8*)(ldsA + aBase + mm*2048 + cb1); } \
    _Pragma("unroll") \
    for (int nn = 0; nn < 4; ++nn) { \
        bfr[nn][0] = *(const bf16x8*)(ldsB + bBase + nn*2048 + cb0); \
        bfr[nn][1] = *(const bf16x8*)(ldsB + bBase + nn*2048 + cb1); } } while(0)

__global__ __launch_bounds__(256, 2) void k_gemm(const __hip_bfloat16* __restrict__ Xall,
                                                 const int* __restrict__ meta,
                                                 u32* __restrict__ rowmax,
                                                 u32* __restrict__ colmax)
{
    const int R = meta[0], Fc = meta[1], Rpad = meta[2];
    const int nbm = (R + 127) >> 7;
    const int nbn = (Fc + 127) >> 7;
    if (nbm == 0 || nbn == 0) return;
    const int Gm = (nbn < 16) ? nbn : 16;
    const int P  = nbm * Gm;

    __shared__ __align__(16) char lds[32768];
    char* ldsA = lds;
    char* ldsB = lds + 16384;

    const int tid = threadIdx.x;
    const int w  = tid >> 6, l = tid & 63;
    const int wm = w >> 1, wn = w & 1;
    const int lg = l >> 4, li = l & 15;
    const int wq = w * 1024;

    // staging geometry: thread covers rows srow+{0,32,64,96}, 8 chunks of
    // 16B per row; pre-swizzled source chunk (tid&7)^(srow&7), linear dest.
    const int srow = tid >> 3;               // 0..31
    const int ch   = ((tid & 7) ^ (srow & 7)) * 16;
    const int soff = srow * ROWB + ch;

    const char* Bb = (const char*)Xall + (size_t)Rpad * ROWB;

    // MFMA read geometry (r7-verified)
    const int aBase = (wm * 64 + li) * 128;
    const int bBase = (wn * 64 + li) * 128;
    const int sw  = li & 7;
    const int cb0 = (lg ^ sw) * 16;
    const int cb1 = ((4 + lg) ^ sw) * 16;

    const float MASKED = -3.0f;
    f32x4 acc[4][4];
    #pragma unroll
    for (int m = 0; m < 4; ++m)
        #pragma unroll
        for (int n = 0; n < 4; ++n)
            acc[m][n] = (f32x4){0.f, 0.f, 0.f, 0.f};

    bf16x8 afr[4][2], bfr[4][2];

    #pragma unroll 1
    for (int p = blockIdx.x; p < P; p += (int)gridDim.x) {
        // ---- decode (bm, grp); XCD-clustered in the common case ----
        int bm, grp;
        if (nbm == 64 && Gm == 16) {
            int xcd = p & 7, i = p >> 3;
            bm = ((i & 7) << 3) + xcd;   // XCD x owns bm == x (mod 8)
            grp = i >> 3;                // [0,16)
        } else {
            bm = p % nbm; grp = p / nbm;
        }
        const int nt = (nbn - grp + Gm - 1) / Gm;
        const int NS = 12 * nt;

        const char* Ab = (const char*)Xall + (size_t)(bm * 128) * ROWB;

        #pragma unroll 1
        for (int th = 0; th < NS; ++th) {
            STAGE(th);
            DRAIN0;                       // stage complete, published
            LOADAB;
            __builtin_amdgcn_s_setprio(1);
            #pragma unroll
            for (int mm = 0; mm < 4; ++mm)
                #pragma unroll
                for (int nn = 0; nn < 4; ++nn) {
                    acc[mm][nn] = MFMA16(afr[mm][0], bfr[nn][0], acc[mm][nn]);
                    acc[mm][nn] = MFMA16(afr[mm][1], bfr[nn][1], acc[mm][nn]);
                }
            __builtin_amdgcn_s_setprio(0);

            if ((th % 12) == 11) {
                // ---- per-bn register epilogue (reads acc only) ----
                const int bnv = grp + Gm * (th / 12);
                #pragma unroll
                for (int m = 0; m < 4; ++m)
                    #pragma unroll
                    for (int reg = 0; reg < 4; ++reg) {
                        float v = MASKED;
                        #pragma unroll
                        for (int n = 0; n < 4; ++n) {
                            int gc = bnv * 128 + wn * 64 + n * 16 + li;
                            v = fmaxf(v, (gc < Fc) ? acc[m][n][reg] : MASKED);
                        }
                        v = fmaxf(v, __shfl_xor(v, 1));
                        v = fmaxf(v, __shfl_xor(v, 2));
                        v = fmaxf(v, __shfl_xor(v, 4));
                        v = fmaxf(v, __shfl_xor(v, 8));
                        int gr = bm * 128 + wm * 64 + m * 16 + lg * 4 + reg;
                        if (li == 0 && gr < R) atomicMax(&rowmax[gr], f2u(v));
                    }
                #pragma unroll
                for (int n = 0; n < 4; ++n) {
                    float v = MASKED;
                    #pragma unroll
                    for (int m = 0; m < 4; ++m)
                        #pragma unroll
                        for (int reg = 0; reg < 4; ++reg) {
                            int gr = bm * 128 + wm * 64 + m * 16 + lg * 4 + reg;
                            v = fmaxf(v, (gr < R) ? acc[m][n][reg] : MASKED);
                        }
                    v = fmaxf(v, __shfl_xor(v, 16));
                    v = fmaxf(v, __shfl_xor(v, 32));
                    int gc = bnv * 128 + wn * 64 + n * 16 + li;
                    if (lg == 0 && gc < Fc) atomicMax(&colmax[gc], f2u(v));
                }
                #pragma unroll
                for (int m = 0; m < 4; ++m)
                    #pragma unroll
                    for (int n = 0; n < 4; ++n)
                        acc[m][n] = (f32x4){0.f, 0.f, 0.f, 0.f};
            }
            BAR;                          // all reads of buffer done
        }
    }
}

// ============================================================================
// K4: maxes -> loss, masked means, scalar out.
// ============================================================================
__global__ void k_final(const u32* __restrict__ rowmax, const u32* __restrict__ colmax,
                        const int* __restrict__ meta, float* __restrict__ out)
{
    const int R = meta[0], Fc = meta[1];
    const int t = threadIdx.x;
    float sr = 0.f, sf = 0.f;
    for (int i = t; i < R; i += 256) {
        u32 u = rowmax[i];
        float m = (u == 0u) ? -1e9f : u2f(u) * INV_TEMP;
        float sg = 1.0f / (1.0f + expf(-m));
        sr += -logf(1.0f - sg + 1e-6f);
    }
    for (int i = t; i < Fc; i += 256) {
        u32 u = colmax[i];
        float m = (u == 0u) ? -1e9f : u2f(u) * INV_TEMP;
        float sg = 1.0f / (1.0f + expf(-m));
        sf += -logf(1.0f - sg + 1e-6f);
    }
    #pragma unroll
    for (int msk = 32; msk >= 1; msk >>= 1) {
        sr += __shfl_xor(sr, msk);
        sf += __shfl_xor(sf, msk);
    }
    __shared__ float r4[4], f4[4];
    if ((t & 63) == 0) { r4[t >> 6] = sr; f4[t >> 6] = sf; }
    __syncthreads();
    if (t == 0) {
        float a = (r4[0] + r4[1] + r4[2] + r4[3]) / (float)((R > 0) ? R : 1);
        float b = (f4[0] + f4[1] + f4[2] + f4[3]) / (float)((Fc > 0) ? Fc : 1);
        out[0] = 0.5f * (a + b);
    }
}

// ============================================================================
extern "C" void kernel_launch(void* const* d_in, const int* in_sizes, int n_in,
                              void* d_out, int out_size, void* d_ws, size_t ws_size,
                              hipStream_t stream)
{
    (void)in_sizes; (void)n_in; (void)out_size; (void)ws_size;
    const float* x    = (const float*)d_in[0];
    const int* labels = (const int*)d_in[1];
    float* out        = (float*)d_out;

    char* ws = (char*)d_ws;
    int* meta = (int*)ws;
    int* pos  = (int*)(ws + 256);
    __hip_bfloat16* Xall = (__hip_bfloat16*)(ws + 131072);
    u32* rowmax = (u32*)(ws + 131072 + XALL_BYTES);
    u32* colmax = rowmax + 16384;

    k_scan<<<1, 256, 0, stream>>>(labels, pos, meta, rowmax);
    k_norm<<<T_TOK / 4, 256, 0, stream>>>(x, labels, pos, meta, Xall);
    k_gemm<<<1024, 256, 0, stream>>>(Xall, meta, rowmax, colmax);
    k_final<<<1, 256, 0, stream>>>(rowmax, colmax, meta, out);
}

// Round 15
// 171.642 us; speedup vs baseline: 1.8818x; 1.1454x over previous
//
#include <hip/hip_runtime.h>
#include <hip/hip_bf16.h>

// Problem constants: B=16, N=1024, D=768 -> T=16384 tokens.
#define T_TOK   16384
#define D_DIM   768
#define ROWB    1536          // bytes per row (768 * 2B bf16)
#define INV_TEMP (1.0f/0.07f)
#define XROWS   17152
#define XALL_BYTES (XROWS * ROWB)

typedef __bf16 bf16x8 __attribute__((ext_vector_type(8)));
typedef float  f32x4  __attribute__((ext_vector_type(4)));
typedef unsigned int u32;
typedef unsigned short u16;

__device__ __forceinline__ u32 f2u(float f) {
    u32 b = __float_as_uint(f);
    return (b & 0x80000000u) ? ~b : (b | 0x80000000u);
}
__device__ __forceinline__ float u2f(u32 u) {
    u32 b = (u & 0x80000000u) ? (u & 0x7FFFFFFFu) : ~u;
    return __uint_as_float(b);
}
__device__ __forceinline__ u16 f2bf(float f) {
    __hip_bfloat16 h = __float2bfloat16(f);
    u16 u; __builtin_memcpy(&u, &h, 2); return u;
}

__device__ __forceinline__ void gload16(const void* g, void* l) {
    __builtin_amdgcn_global_load_lds((const __attribute__((address_space(1))) u32*)g,
                                     (__attribute__((address_space(3))) u32*)l,
                                     16, 0, 0);
}

// ============================================================================
// K1: class-wise prefix scan + fused zeroing of rowmax/colmax.
// meta[0]=R, meta[1]=F, meta[2]=Rpad(256-aligned).
// ============================================================================
__global__ void k_scan(const int* __restrict__ labels, int* __restrict__ pos,
                       int* __restrict__ meta, u32* __restrict__ rowmax)
{
    __shared__ int sr[256], sf[256];
    const int t = threadIdx.x;
    for (int i = t; i < 32768; i += 256) rowmax[i] = 0u;
    const int base = t * 64;
    int cr = 0, cf = 0;
    for (int i = 0; i < 64; ++i) {
        int v = labels[base + i];
        cr += (v == 0);
        cf += (v == 1);
    }
    sr[t] = cr; sf[t] = cf;
    __syncthreads();
    if (t == 0) {
        int ar = 0, af = 0;
        for (int i = 0; i < 256; ++i) {
            int r = sr[i]; sr[i] = ar; ar += r;
            int f = sf[i]; sf[i] = af; af += f;
        }
        meta[0] = ar;
        meta[1] = af;
        meta[2] = (ar + 255) & ~255;
    }
    __syncthreads();
    int pr = sr[t], pf = sf[t];
    for (int i = 0; i < 64; ++i) {
        int v = labels[base + i];
        pos[base + i] = (v == 0) ? pr++ : pf++;
    }
}

// ============================================================================
// K2: L2-normalize, wave-per-row (4 rows/block): 64 lanes x 3 float4 = 768
// floats; pure shuffle reduce (no LDS, no block barrier, no idle lanes).
// ============================================================================
__global__ void k_norm(const float* __restrict__ x, const int* __restrict__ labels,
                       const int* __restrict__ pos, const int* __restrict__ meta,
                       __hip_bfloat16* __restrict__ Xall)
{
    const int t = threadIdx.x;
    const int wv = t >> 6, ln = t & 63;
    const int row = blockIdx.x * 4 + wv;
    const float4* xr = (const float4*)(x + (size_t)row * D_DIM);
    float4 v0 = xr[ln], v1 = xr[ln + 64], v2 = xr[ln + 128];
    float ss = v0.x*v0.x + v0.y*v0.y + v0.z*v0.z + v0.w*v0.w
             + v1.x*v1.x + v1.y*v1.y + v1.z*v1.z + v1.w*v1.w
             + v2.x*v2.x + v2.y*v2.y + v2.z*v2.z + v2.w*v2.w;
    #pragma unroll
    for (int m = 32; m >= 1; m >>= 1) ss += __shfl_xor(ss, m);
    float inv = 1.0f / fmaxf(sqrtf(ss), 1e-12f);
    int lab = labels[row];
    int base = (lab == 0) ? pos[row] : (meta[2] + pos[row]);
    ushort4* dst = (ushort4*)(Xall + (size_t)base * D_DIM);
    ushort4 o0, o1, o2;
    o0.x = f2bf(v0.x*inv); o0.y = f2bf(v0.y*inv); o0.z = f2bf(v0.z*inv); o0.w = f2bf(v0.w*inv);
    o1.x = f2bf(v1.x*inv); o1.y = f2bf(v1.y*inv); o1.z = f2bf(v1.z*inv); o1.w = f2bf(v1.w*inv);
    o2.x = f2bf(v2.x*inv); o2.y = f2bf(v2.y*inv); o2.z = f2bf(v2.z*inv); o2.w = f2bf(v2.w*inv);
    dst[ln]       = o0;
    dst[ln + 64]  = o1;
    dst[ln + 128] = o2;
}

// ============================================================================
// K3 (round 15 = r10 verbatim, session best: k_gemm ~137us, absmax 0 twice).
// 128x128 tile, 4 waves 2x2, A+B LDS double buffer 64 KiB, 2 blocks/CU,
// streaming bn, XCD decode. T14 issue-early/wait-late, counting-free:
//   TILE(b,t): STAGE_A(b^1,t+1); STAGE_B(b^1,t+1);   // issue at tile START
//              LOAD_A(b); LOAD_B0(b); MM(0); LOAD_B1(b); MM(2);
//              DRAIN0;                                // vmcnt(0); s_barrier
// RAW: each wave's vmcnt(0) forces its OWN stage-writes before the barrier;
// barrier publishes. WAR: tile reads consumed (lgkm) before barrier arrival;
// next write to that buffer issues after. No vmcnt counting assumptions.
// ============================================================================
#define MFMA16(a,b,c) __builtin_amdgcn_mfma_f32_16x16x32_bf16(a,b,c,0,0,0)

#define LA(b)  (lds + (b)*32768)
#define LBr(b) (lds + (b)*32768 + 16384)

// step s -> (bi=s/12, kt=s%12); wave-uniform scalar math.
#define STAGE_A(b,s) do { \
    int kt_ = (s) % 12; \
    const char* ap_ = Ab + aoff + kt_*128; \
    gload16(ap_,           LA(b) + wq); \
    gload16(ap_ +  49152,  LA(b) + wq + 4096); \
    gload16(ap_ +  98304,  LA(b) + wq + 8192); \
    gload16(ap_ + 147456,  LA(b) + wq + 12288); } while(0)
#define STAGE_B(b,s) do { \
    int bi_ = (s)/12, kt_ = (s)%12; \
    const char* bp_ = Bb + (size_t)(grp + Gm*bi_) * (128*ROWB) + aoff + kt_*128; \
    gload16(bp_,           LBr(b) + wq); \
    gload16(bp_ +  49152,  LBr(b) + wq + 4096); \
    gload16(bp_ +  98304,  LBr(b) + wq + 8192); \
    gload16(bp_ + 147456,  LBr(b) + wq + 12288); } while(0)

#define DRAIN0 asm volatile("s_waitcnt vmcnt(0)\n\ts_barrier" ::: "memory")

#define LOAD_A(b) do { \
    _Pragma("unroll") \
    for (int mm = 0; mm < 4; ++mm) { \
        afr[mm][0] = *(const bf16x8*)(LA(b) + aBase + mm*2048 + cb0); \
        afr[mm][1] = *(const bf16x8*)(LA(b) + aBase + mm*2048 + cb1); } } while(0)
#define LOAD_B0(b) do { \
    _Pragma("unroll") \
    for (int nn = 0; nn < 2; ++nn) { \
        bfrA[nn][0] = *(const bf16x8*)(LBr(b) + bBase + nn*2048 + cb0); \
        bfrA[nn][1] = *(const bf16x8*)(LBr(b) + bBase + nn*2048 + cb1); } } while(0)
#define LOAD_B1(b) do { \
    _Pragma("unroll") \
    for (int nn = 0; nn < 2; ++nn) { \
        bfrB[nn][0] = *(const bf16x8*)(LBr(b) + bBase + (2+nn)*2048 + cb0); \
        bfrB[nn][1] = *(const bf16x8*)(LBr(b) + bBase + (2+nn)*2048 + cb1); } } while(0)

#define MM(nbase,bvx) do { \
    __builtin_amdgcn_s_setprio(1); \
    _Pragma("unroll") \
    for (int mm = 0; mm < 4; ++mm) { \
        _Pragma("unroll") \
        for (int nn = 0; nn < 2; ++nn) { \
            acc[mm][(nbase)+nn] = MFMA16(afr[mm][0], bvx[nn][0], acc[mm][(nbase)+nn]); \
            acc[mm][(nbase)+nn] = MFMA16(afr[mm][1], bvx[nn][1], acc[mm][(nbase)+nn]); } } \
    __builtin_amdgcn_s_setprio(0); \
} while(0)

#define TILE(b,t) do { \
    int s_ = (t)+1; if (s_ > NS-1) s_ = NS-1; \
    STAGE_A((b)^1, s_); \
    STAGE_B((b)^1, s_); \
    LOAD_A(b); LOAD_B0(b); \
    MM(0, bfrA); \
    LOAD_B1(b); \
    MM(2, bfrB); \
    DRAIN0; \
} while(0)

__global__ __launch_bounds__(256, 2) void k_gemm(const __hip_bfloat16* __restrict__ Xall,
                                                 const int* __restrict__ meta,
                                                 u32* __restrict__ rowmax,
                                                 u32* __restrict__ colmax)
{
    const int R = meta[0], Fc = meta[1], Rpad = meta[2];
    const int nbm = (R + 127) >> 7;
    const int nbn = (Fc + 127) >> 7;
    if (nbm == 0 || nbn == 0) return;
    const int Gm = (nbn < 8) ? nbn : 8;
    const int P  = nbm * Gm;

    __shared__ __align__(16) char lds[65536];

    const int tid = threadIdx.x;
    const int w  = tid >> 6, l = tid & 63;
    const int wm = w >> 1, wn = w & 1;
    const int lg = l >> 4, li = l & 15;
    const int wq = w * 1024;

    // staging geometry: thread covers row (tid>>3) + i*32, chunk (tid&7)^(row&7)
    const int srow = tid >> 3;
    const int ch   = ((tid & 7) ^ (srow & 7)) * 16;
    const int aoff = srow * ROWB + ch;

    const char* Bb = (const char*)Xall + (size_t)Rpad * ROWB;

    // MFMA read geometry
    const int aBase = (wm * 64 + li) * 128;
    const int bBase = (wn * 64 + li) * 128;
    const int sw  = li & 7;
    const int cb0 = (lg ^ sw) * 16;
    const int cb1 = ((4 + lg) ^ sw) * 16;

    const float MASKED = -3.0f;
    f32x4 acc[4][4];
    #pragma unroll
    for (int m = 0; m < 4; ++m)
        #pragma unroll
        for (int n = 0; n < 4; ++n)
            acc[m][n] = (f32x4){0.f, 0.f, 0.f, 0.f};

    bf16x8 afr[4][2], bfrA[2][2], bfrB[2][2];

    #pragma unroll 1
    for (int p = blockIdx.x; p < P; p += 512) {
        // ---- decode (bm, grp); XCD-clustered in the common case ----
        int bm, grp;
        if (nbm == 64 && Gm == 8) {
            int xcd = p & 7, i = p >> 3;
            bm = ((i & 7) << 3) + xcd;   // XCD x owns bm == x (mod 8)
            grp = i >> 3;
        } else {
            bm = p % nbm; grp = p / nbm;
        }
        const int nt = (nbn - grp + Gm - 1) / Gm;
        const int NS = 12 * nt;

        const char* Ab = (const char*)Xall + (size_t)(bm * 128) * ROWB;

        // prologue: tile0 A+B -> buf0; drain (also clears prior-stream vm ops)
        STAGE_A(0, 0); STAGE_B(0, 0);
        DRAIN0;

        #pragma unroll 1
        for (int th = 0; th < NS; th += 2) {
            TILE(0, th);
            TILE(1, th + 1);

            if (((th + 1) % 12) == 11) {
                // ---- per-bn register epilogue (no barriers) ----
                const int bnv = grp + Gm * ((th + 1) / 12);
                #pragma unroll
                for (int m = 0; m < 4; ++m)
                    #pragma unroll
                    for (int reg = 0; reg < 4; ++reg) {
                        float v = MASKED;
                        #pragma unroll
                        for (int n = 0; n < 4; ++n) {
                            int gc = bnv * 128 + wn * 64 + n * 16 + li;
                            v = fmaxf(v, (gc < Fc) ? acc[m][n][reg] : MASKED);
                        }
                        v = fmaxf(v, __shfl_xor(v, 1));
                        v = fmaxf(v, __shfl_xor(v, 2));
                        v = fmaxf(v, __shfl_xor(v, 4));
                        v = fmaxf(v, __shfl_xor(v, 8));
                        int gr = bm * 128 + wm * 64 + m * 16 + lg * 4 + reg;
                        if (li == 0 && gr < R) atomicMax(&rowmax[gr], f2u(v));
                    }
                #pragma unroll
                for (int n = 0; n < 4; ++n) {
                    float v = MASKED;
                    #pragma unroll
                    for (int m = 0; m < 4; ++m)
                        #pragma unroll
                        for (int reg = 0; reg < 4; ++reg) {
                            int gr = bm * 128 + wm * 64 + m * 16 + lg * 4 + reg;
                            v = fmaxf(v, (gr < R) ? acc[m][n][reg] : MASKED);
                        }
                    v = fmaxf(v, __shfl_xor(v, 16));
                    v = fmaxf(v, __shfl_xor(v, 32));
                    int gc = bnv * 128 + wn * 64 + n * 16 + li;
                    if (lg == 0 && gc < Fc) atomicMax(&colmax[gc], f2u(v));
                }
                #pragma unroll
                for (int m = 0; m < 4; ++m)
                    #pragma unroll
                    for (int n = 0; n < 4; ++n)
                        acc[m][n] = (f32x4){0.f, 0.f, 0.f, 0.f};
            }
        }
    }
}

// ============================================================================
// K4: maxes -> loss, masked means, scalar out.
// ============================================================================
__global__ void k_final(const u32* __restrict__ rowmax, const u32* __restrict__ colmax,
                        const int* __restrict__ meta, float* __restrict__ out)
{
    const int R = meta[0], Fc = meta[1];
    const int t = threadIdx.x;
    float sr = 0.f, sf = 0.f;
    for (int i = t; i < R; i += 256) {
        u32 u = rowmax[i];
        float m = (u == 0u) ? -1e9f : u2f(u) * INV_TEMP;
        float sg = 1.0f / (1.0f + expf(-m));
        sr += -logf(1.0f - sg + 1e-6f);
    }
    for (int i = t; i < Fc; i += 256) {
        u32 u = colmax[i];
        float m = (u == 0u) ? -1e9f : u2f(u) * INV_TEMP;
        float sg = 1.0f / (1.0f + expf(-m));
        sf += -logf(1.0f - sg + 1e-6f);
    }
    #pragma unroll
    for (int msk = 32; msk >= 1; msk >>= 1) {
        sr += __shfl_xor(sr, msk);
        sf += __shfl_xor(sf, msk);
    }
    __shared__ float r4[4], f4[4];
    if ((t & 63) == 0) { r4[t >> 6] = sr; f4[t >> 6] = sf; }
    __syncthreads();
    if (t == 0) {
        float a = (r4[0] + r4[1] + r4[2] + r4[3]) / (float)((R > 0) ? R : 1);
        float b = (f4[0] + f4[1] + f4[2] + f4[3]) / (float)((Fc > 0) ? Fc : 1);
        out[0] = 0.5f * (a + b);
    }
}

// ============================================================================
extern "C" void kernel_launch(void* const* d_in, const int* in_sizes, int n_in,
                              void* d_out, int out_size, void* d_ws, size_t ws_size,
                              hipStream_t stream)
{
    (void)in_sizes; (void)n_in; (void)out_size; (void)ws_size;
    const float* x    = (const float*)d_in[0];
    const int* labels = (const int*)d_in[1];
    float* out        = (float*)d_out;

    char* ws = (char*)d_ws;
    int* meta = (int*)ws;
    int* pos  = (int*)(ws + 256);
    __hip_bfloat16* Xall = (__hip_bfloat16*)(ws + 131072);
    u32* rowmax = (u32*)(ws + 131072 + XALL_BYTES);
    u32* colmax = rowmax + 16384;

    k_scan<<<1, 256, 0, stream>>>(labels, pos, meta, rowmax);
    k_norm<<<T_TOK / 4, 256, 0, stream>>>(x, labels, pos, meta, Xall);
    k_gemm<<<512, 256, 0, stream>>>(Xall, meta, rowmax, colmax);
    k_final<<<1, 256, 0, stream>>>(rowmax, colmax, meta, out);
}

// Round 16
// 150.348 us; speedup vs baseline: 2.1483x; 1.1416x over previous
//
#include <hip/hip_runtime.h>
#include <hip/hip_bf16.h>

// Problem constants: B=16, N=1024, D=768 -> T=16384 tokens.
#define T_TOK   16384
#define D_DIM   768
#define ROWB    1536          // bytes per row (768 * 2B bf16)
#define INV_TEMP (1.0f/0.07f)
#define XROWS   17152
#define XALL_BYTES (XROWS * ROWB)

typedef __bf16 bf16x8 __attribute__((ext_vector_type(8)));
typedef float  f32x4  __attribute__((ext_vector_type(4)));
typedef unsigned int u32;
typedef unsigned short u16;

__device__ __forceinline__ u32 f2u(float f) {
    u32 b = __float_as_uint(f);
    return (b & 0x80000000u) ? ~b : (b | 0x80000000u);
}
__device__ __forceinline__ float u2f(u32 u) {
    u32 b = (u & 0x80000000u) ? (u & 0x7FFFFFFFu) : ~u;
    return __uint_as_float(b);
}
__device__ __forceinline__ u16 f2bf(float f) {
    __hip_bfloat16 h = __float2bfloat16(f);
    u16 u; __builtin_memcpy(&u, &h, 2); return u;
}

__device__ __forceinline__ void gload16(const void* g, void* l) {
    __builtin_amdgcn_global_load_lds((const __attribute__((address_space(1))) u32*)g,
                                     (__attribute__((address_space(3))) u32*)l,
                                     16, 0, 0);
}

// ============================================================================
// K1 (round 16): class-wise prefix scan, PARALLEL (shuffle scan, int4 I/O)
// + fused zeroing of rowmax/colmax. Same deterministic class-order semantics
// as the serial version: thread t's tokens occupy positions after the counts
// of threads 0..t-1 in label order.
// meta[0]=R, meta[1]=F, meta[2]=Rpad(256-aligned).
// ============================================================================
__global__ void k_scan(const int* __restrict__ labels, int* __restrict__ pos,
                       int* __restrict__ meta, u32* __restrict__ rowmax)
{
    const int t = threadIdx.x;
    for (int i = t; i < 32768; i += 256) rowmax[i] = 0u;

    const int base = t * 64;
    const int4* lab4 = (const int4*)(labels + base);
    int cr = 0, cf = 0;
    #pragma unroll
    for (int i = 0; i < 16; ++i) {
        int4 v = lab4[i];
        cr += (v.x == 0) + (v.y == 0) + (v.z == 0) + (v.w == 0);
        cf += (v.x == 1) + (v.y == 1) + (v.z == 1) + (v.w == 1);
    }
    // wave-level inclusive scan
    int ir = cr, ifk = cf;
    #pragma unroll
    for (int d = 1; d < 64; d <<= 1) {
        int vr = __shfl_up(ir, d);
        int vf = __shfl_up(ifk, d);
        if ((t & 63) >= d) { ir += vr; ifk += vf; }
    }
    __shared__ int wr[4], wf[4];
    if ((t & 63) == 63) { wr[t >> 6] = ir; wf[t >> 6] = ifk; }
    __syncthreads();
    const int wid = t >> 6;
    int wbr = 0, wbf = 0;
    #pragma unroll
    for (int k = 0; k < 4; ++k)
        if (k < wid) { wbr += wr[k]; wbf += wf[k]; }
    if (t == 0) {
        int R = wr[0] + wr[1] + wr[2] + wr[3];
        int F = wf[0] + wf[1] + wf[2] + wf[3];
        meta[0] = R;
        meta[1] = F;
        meta[2] = (R + 255) & ~255;
    }
    int pr = wbr + ir - cr;     // exclusive prefix (real)
    int pf = wbf + ifk - cf;    // exclusive prefix (fake)
    int4* pos4 = (int4*)(pos + base);
    #pragma unroll
    for (int i = 0; i < 16; ++i) {
        int4 v = lab4[i];
        int4 o;
        o.x = (v.x == 0) ? pr++ : pf++;
        o.y = (v.y == 0) ? pr++ : pf++;
        o.z = (v.z == 0) ? pr++ : pf++;
        o.w = (v.w == 0) ? pr++ : pf++;
        pos4[i] = o;
    }
}

// ============================================================================
// K2: L2-normalize, wave-per-row (4 rows/block): 64 lanes x 3 float4 = 768
// floats; pure shuffle reduce (no LDS, no block barrier, no idle lanes).
// ============================================================================
__global__ void k_norm(const float* __restrict__ x, const int* __restrict__ labels,
                       const int* __restrict__ pos, const int* __restrict__ meta,
                       __hip_bfloat16* __restrict__ Xall)
{
    const int t = threadIdx.x;
    const int wv = t >> 6, ln = t & 63;
    const int row = blockIdx.x * 4 + wv;
    const float4* xr = (const float4*)(x + (size_t)row * D_DIM);
    float4 v0 = xr[ln], v1 = xr[ln + 64], v2 = xr[ln + 128];
    float ss = v0.x*v0.x + v0.y*v0.y + v0.z*v0.z + v0.w*v0.w
             + v1.x*v1.x + v1.y*v1.y + v1.z*v1.z + v1.w*v1.w
             + v2.x*v2.x + v2.y*v2.y + v2.z*v2.z + v2.w*v2.w;
    #pragma unroll
    for (int m = 32; m >= 1; m >>= 1) ss += __shfl_xor(ss, m);
    float inv = 1.0f / fmaxf(sqrtf(ss), 1e-12f);
    int lab = labels[row];
    int base = (lab == 0) ? pos[row] : (meta[2] + pos[row]);
    ushort4* dst = (ushort4*)(Xall + (size_t)base * D_DIM);
    ushort4 o0, o1, o2;
    o0.x = f2bf(v0.x*inv); o0.y = f2bf(v0.y*inv); o0.z = f2bf(v0.z*inv); o0.w = f2bf(v0.w*inv);
    o1.x = f2bf(v1.x*inv); o1.y = f2bf(v1.y*inv); o1.z = f2bf(v1.z*inv); o1.w = f2bf(v1.w*inv);
    o2.x = f2bf(v2.x*inv); o2.y = f2bf(v2.y*inv); o2.z = f2bf(v2.z*inv); o2.w = f2bf(v2.w*inv);
    dst[ln]       = o0;
    dst[ln + 64]  = o1;
    dst[ln + 128] = o2;
}

// ============================================================================
// K3 (FROZEN = r10/r15 verbatim, session best: k_gemm ~137us, absmax 0 x3).
// 128x128 tile, 4 waves 2x2, A+B LDS double buffer 64 KiB, 2 blocks/CU,
// streaming bn, XCD decode. T14 issue-early/wait-late, counting-free:
//   TILE(b,t): STAGE_A(b^1,t+1); STAGE_B(b^1,t+1);   // issue at tile START
//              LOAD_A(b); LOAD_B0(b); MM(0); LOAD_B1(b); MM(2);
//              DRAIN0;                                // vmcnt(0); s_barrier
// RAW: each wave's vmcnt(0) forces its OWN stage-writes before the barrier;
// barrier publishes. WAR: tile reads consumed (lgkm) before barrier arrival;
// next write to that buffer issues after. No vmcnt counting assumptions.
// ============================================================================
#define MFMA16(a,b,c) __builtin_amdgcn_mfma_f32_16x16x32_bf16(a,b,c,0,0,0)

#define LA(b)  (lds + (b)*32768)
#define LBr(b) (lds + (b)*32768 + 16384)

// step s -> (bi=s/12, kt=s%12); wave-uniform scalar math.
#define STAGE_A(b,s) do { \
    int kt_ = (s) % 12; \
    const char* ap_ = Ab + aoff + kt_*128; \
    gload16(ap_,           LA(b) + wq); \
    gload16(ap_ +  49152,  LA(b) + wq + 4096); \
    gload16(ap_ +  98304,  LA(b) + wq + 8192); \
    gload16(ap_ + 147456,  LA(b) + wq + 12288); } while(0)
#define STAGE_B(b,s) do { \
    int bi_ = (s)/12, kt_ = (s)%12; \
    const char* bp_ = Bb + (size_t)(grp + Gm*bi_) * (128*ROWB) + aoff + kt_*128; \
    gload16(bp_,           LBr(b) + wq); \
    gload16(bp_ +  49152,  LBr(b) + wq + 4096); \
    gload16(bp_ +  98304,  LBr(b) + wq + 8192); \
    gload16(bp_ + 147456,  LBr(b) + wq + 12288); } while(0)

#define DRAIN0 asm volatile("s_waitcnt vmcnt(0)\n\ts_barrier" ::: "memory")

#define LOAD_A(b) do { \
    _Pragma("unroll") \
    for (int mm = 0; mm < 4; ++mm) { \
        afr[mm][0] = *(const bf16x8*)(LA(b) + aBase + mm*2048 + cb0); \
        afr[mm][1] = *(const bf16x8*)(LA(b) + aBase + mm*2048 + cb1); } } while(0)
#define LOAD_B0(b) do { \
    _Pragma("unroll") \
    for (int nn = 0; nn < 2; ++nn) { \
        bfrA[nn][0] = *(const bf16x8*)(LBr(b) + bBase + nn*2048 + cb0); \
        bfrA[nn][1] = *(const bf16x8*)(LBr(b) + bBase + nn*2048 + cb1); } } while(0)
#define LOAD_B1(b) do { \
    _Pragma("unroll") \
    for (int nn = 0; nn < 2; ++nn) { \
        bfrB[nn][0] = *(const bf16x8*)(LBr(b) + bBase + (2+nn)*2048 + cb0); \
        bfrB[nn][1] = *(const bf16x8*)(LBr(b) + bBase + (2+nn)*2048 + cb1); } } while(0)

#define MM(nbase,bvx) do { \
    __builtin_amdgcn_s_setprio(1); \
    _Pragma("unroll") \
    for (int mm = 0; mm < 4; ++mm) { \
        _Pragma("unroll") \
        for (int nn = 0; nn < 2; ++nn) { \
            acc[mm][(nbase)+nn] = MFMA16(afr[mm][0], bvx[nn][0], acc[mm][(nbase)+nn]); \
            acc[mm][(nbase)+nn] = MFMA16(afr[mm][1], bvx[nn][1], acc[mm][(nbase)+nn]); } } \
    __builtin_amdgcn_s_setprio(0); \
} while(0)

#define TILE(b,t) do { \
    int s_ = (t)+1; if (s_ > NS-1) s_ = NS-1; \
    STAGE_A((b)^1, s_); \
    STAGE_B((b)^1, s_); \
    LOAD_A(b); LOAD_B0(b); \
    MM(0, bfrA); \
    LOAD_B1(b); \
    MM(2, bfrB); \
    DRAIN0; \
} while(0)

__global__ __launch_bounds__(256, 2) void k_gemm(const __hip_bfloat16* __restrict__ Xall,
                                                 const int* __restrict__ meta,
                                                 u32* __restrict__ rowmax,
                                                 u32* __restrict__ colmax)
{
    const int R = meta[0], Fc = meta[1], Rpad = meta[2];
    const int nbm = (R + 127) >> 7;
    const int nbn = (Fc + 127) >> 7;
    if (nbm == 0 || nbn == 0) return;
    const int Gm = (nbn < 8) ? nbn : 8;
    const int P  = nbm * Gm;

    __shared__ __align__(16) char lds[65536];

    const int tid = threadIdx.x;
    const int w  = tid >> 6, l = tid & 63;
    const int wm = w >> 1, wn = w & 1;
    const int lg = l >> 4, li = l & 15;
    const int wq = w * 1024;

    // staging geometry: thread covers row (tid>>3) + i*32, chunk (tid&7)^(row&7)
    const int srow = tid >> 3;
    const int ch   = ((tid & 7) ^ (srow & 7)) * 16;
    const int aoff = srow * ROWB + ch;

    const char* Bb = (const char*)Xall + (size_t)Rpad * ROWB;

    // MFMA read geometry
    const int aBase = (wm * 64 + li) * 128;
    const int bBase = (wn * 64 + li) * 128;
    const int sw  = li & 7;
    const int cb0 = (lg ^ sw) * 16;
    const int cb1 = ((4 + lg) ^ sw) * 16;

    const float MASKED = -3.0f;
    f32x4 acc[4][4];
    #pragma unroll
    for (int m = 0; m < 4; ++m)
        #pragma unroll
        for (int n = 0; n < 4; ++n)
            acc[m][n] = (f32x4){0.f, 0.f, 0.f, 0.f};

    bf16x8 afr[4][2], bfrA[2][2], bfrB[2][2];

    #pragma unroll 1
    for (int p = blockIdx.x; p < P; p += 512) {
        // ---- decode (bm, grp); XCD-clustered in the common case ----
        int bm, grp;
        if (nbm == 64 && Gm == 8) {
            int xcd = p & 7, i = p >> 3;
            bm = ((i & 7) << 3) + xcd;   // XCD x owns bm == x (mod 8)
            grp = i >> 3;
        } else {
            bm = p % nbm; grp = p / nbm;
        }
        const int nt = (nbn - grp + Gm - 1) / Gm;
        const int NS = 12 * nt;

        const char* Ab = (const char*)Xall + (size_t)(bm * 128) * ROWB;

        // prologue: tile0 A+B -> buf0; drain (also clears prior-stream vm ops)
        STAGE_A(0, 0); STAGE_B(0, 0);
        DRAIN0;

        #pragma unroll 1
        for (int th = 0; th < NS; th += 2) {
            TILE(0, th);
            TILE(1, th + 1);

            if (((th + 1) % 12) == 11) {
                // ---- per-bn register epilogue (no barriers) ----
                const int bnv = grp + Gm * ((th + 1) / 12);
                #pragma unroll
                for (int m = 0; m < 4; ++m)
                    #pragma unroll
                    for (int reg = 0; reg < 4; ++reg) {
                        float v = MASKED;
                        #pragma unroll
                        for (int n = 0; n < 4; ++n) {
                            int gc = bnv * 128 + wn * 64 + n * 16 + li;
                            v = fmaxf(v, (gc < Fc) ? acc[m][n][reg] : MASKED);
                        }
                        v = fmaxf(v, __shfl_xor(v, 1));
                        v = fmaxf(v, __shfl_xor(v, 2));
                        v = fmaxf(v, __shfl_xor(v, 4));
                        v = fmaxf(v, __shfl_xor(v, 8));
                        int gr = bm * 128 + wm * 64 + m * 16 + lg * 4 + reg;
                        if (li == 0 && gr < R) atomicMax(&rowmax[gr], f2u(v));
                    }
                #pragma unroll
                for (int n = 0; n < 4; ++n) {
                    float v = MASKED;
                    #pragma unroll
                    for (int m = 0; m < 4; ++m)
                        #pragma unroll
                        for (int reg = 0; reg < 4; ++reg) {
                            int gr = bm * 128 + wm * 64 + m * 16 + lg * 4 + reg;
                            v = fmaxf(v, (gr < R) ? acc[m][n][reg] : MASKED);
                        }
                    v = fmaxf(v, __shfl_xor(v, 16));
                    v = fmaxf(v, __shfl_xor(v, 32));
                    int gc = bnv * 128 + wn * 64 + n * 16 + li;
                    if (lg == 0 && gc < Fc) atomicMax(&colmax[gc], f2u(v));
                }
                #pragma unroll
                for (int m = 0; m < 4; ++m)
                    #pragma unroll
                    for (int n = 0; n < 4; ++n)
                        acc[m][n] = (f32x4){0.f, 0.f, 0.f, 0.f};
            }
        }
    }
}

// ============================================================================
// K4 (round 16): maxes -> loss, masked means, scalar out. 1024 threads
// (16 serial transcendental iterations/thread instead of 64).
// ============================================================================
__global__ void k_final(const u32* __restrict__ rowmax, const u32* __restrict__ colmax,
                        const int* __restrict__ meta, float* __restrict__ out)
{
    const int R = meta[0], Fc = meta[1];
    const int t = threadIdx.x;
    float sr = 0.f, sf = 0.f;
    for (int i = t; i < R; i += 1024) {
        u32 u = rowmax[i];
        float m = (u == 0u) ? -1e9f : u2f(u) * INV_TEMP;
        float sg = 1.0f / (1.0f + expf(-m));
        sr += -logf(1.0f - sg + 1e-6f);
    }
    for (int i = t; i < Fc; i += 1024) {
        u32 u = colmax[i];
        float m = (u == 0u) ? -1e9f : u2f(u) * INV_TEMP;
        float sg = 1.0f / (1.0f + expf(-m));
        sf += -logf(1.0f - sg + 1e-6f);
    }
    #pragma unroll
    for (int msk = 32; msk >= 1; msk >>= 1) {
        sr += __shfl_xor(sr, msk);
        sf += __shfl_xor(sf, msk);
    }
    __shared__ float r16[16], f16[16];
    if ((t & 63) == 0) { r16[t >> 6] = sr; f16[t >> 6] = sf; }
    __syncthreads();
    if (t == 0) {
        float a = 0.f, b = 0.f;
        #pragma unroll
        for (int k = 0; k < 16; ++k) { a += r16[k]; b += f16[k]; }
        a /= (float)((R > 0) ? R : 1);
        b /= (float)((Fc > 0) ? Fc : 1);
        out[0] = 0.5f * (a + b);
    }
}

// ============================================================================
extern "C" void kernel_launch(void* const* d_in, const int* in_sizes, int n_in,
                              void* d_out, int out_size, void* d_ws, size_t ws_size,
                              hipStream_t stream)
{
    (void)in_sizes; (void)n_in; (void)out_size; (void)ws_size;
    const float* x    = (const float*)d_in[0];
    const int* labels = (const int*)d_in[1];
    float* out        = (float*)d_out;

    char* ws = (char*)d_ws;
    int* meta = (int*)ws;
    int* pos  = (int*)(ws + 256);
    __hip_bfloat16* Xall = (__hip_bfloat16*)(ws + 131072);
    u32* rowmax = (u32*)(ws + 131072 + XALL_BYTES);
    u32* colmax = rowmax + 16384;

    k_scan<<<1, 256, 0, stream>>>(labels, pos, meta, rowmax);
    k_norm<<<T_TOK / 4, 256, 0, stream>>>(x, labels, pos, meta, Xall);
    k_gemm<<<512, 256, 0, stream>>>(Xall, meta, rowmax, colmax);
    k_final<<<1, 1024, 0, stream>>>(rowmax, colmax, meta, out);
}